// Round 4
// baseline (228.816 us; speedup 1.0000x reference)
//
#include <hip/hip_runtime.h>
#include <string.h>

typedef _Float16 f16x8 __attribute__((ext_vector_type(8)));
typedef float    f32x16 __attribute__((ext_vector_type(16)));

#define HWSZ   1024
#define DDIM   256
#define KCODES 1024
#define NROWS  65536
#define TAU    0.05f     // dot-space gap threshold for exact-recheck
#define NINF  -3.4e38f

union U16 { uint4 u; f16x8 h; };

// ---------------- e2[k] = sum_d embed[d][k]^2 (4 threads per code) ----------------
__global__ void e2_kernel(const float* __restrict__ embed,
                          float* __restrict__ e2, float* __restrict__ e2n) {
    int id = blockIdx.x * 256 + threadIdx.x;   // 4096 threads
    int k = id >> 2, q = id & 3;
    float s = 0.f;
#pragma unroll 8
    for (int dd = 0; dd < 64; ++dd) {
        float v = embed[(size_t)(q * 64 + dd) * KCODES + k];
        s = fmaf(v, v, s);
    }
    s += __shfl_xor(s, 1, 64);
    s += __shfl_xor(s, 2, 64);
    if (q == 0) { e2[k] = s; e2n[k] = -0.5f * s; }
}

// ---------------- prep: fp16(embed) in MFMA-A lane order ----------------
// ehat[step*512 + cfg*64 + slot] (uint4 = 8 fp16): code = (step>>4)*256 + cfg*32 + (slot&31),
// d = (step&15)*16 + (slot>>5)*8 + j
__global__ void prep_e(const float* __restrict__ embed, uint4* __restrict__ ehat) {
    int id = blockIdx.x * 256 + threadIdx.x;   // 32768
    int slot = id & 63;
    int cfg  = (id >> 6) & 7;
    int step = id >> 9;                        // 0..63
    int code = (step >> 4) * 256 + cfg * 32 + (slot & 31);
    int dbase = (step & 15) * 16 + (slot >> 5) * 8;
    _Float16 h[8];
#pragma unroll
    for (int j = 0; j < 8; ++j)
        h[j] = (_Float16)embed[(size_t)(dbase + j) * KCODES + code];
    uint4 o;
    __builtin_memcpy(&o, h, 16);
    ehat[id] = o;
}

// ---------------- main: 2-term fp16 split, E in regs, barrier-free K-loop ----------------
__global__ __launch_bounds__(256, 2)
void vq_main(const float* __restrict__ x, const uint4* __restrict__ ehat,
             const float* __restrict__ e2n,
             int* __restrict__ ind, int* __restrict__ count, int* __restrict__ list) {
    __shared__ __align__(16) char XS[65536];   // [g2][ks16][hl2][kg2][pl32] x 16B

    const int t    = threadIdx.x;
    const int lane = t & 63;
    const int w    = t >> 6;       // wave = code quarter within chunk
    const int kg   = lane >> 5;
    const int l31  = lane & 31;

    const int pix0 = blockIdx.x * 64;
    const int b0   = pix0 >> 10;
    const int hw0  = pix0 & 1023;
    const float* xb = x + (size_t)b0 * (DDIM * HWSZ) + hw0;

    // ---- stage X tile: f32 -> fp16 hi/lo fragments ----
    {
        int pix = t & 63;
        int g = pix >> 5, pl = pix & 31;
        const float* xpix = xb + pix;
        char* xsg = XS + g * 32768 + pl * 16;
#pragma unroll
        for (int it = 0; it < 8; ++it) {
            int p = it * 4 + w;            // ks = p>>1, kg = p&1
            int d0 = p * 8;
            float v[8];
#pragma unroll
            for (int j = 0; j < 8; ++j) v[j] = xpix[(size_t)(d0 + j) * HWSZ];
            _Float16 h[8], l[8];
#pragma unroll
            for (int j = 0; j < 8; ++j) {
                h[j] = (_Float16)v[j];
                l[j] = (_Float16)(v[j] - (float)h[j]);
            }
            uint4 hv, lv;
            __builtin_memcpy(&hv, h, 16);
            __builtin_memcpy(&lv, l, 16);
            char* base = xsg + (p >> 1) * 2048 + ((p & 1) << 9);
            *(uint4*)base = hv;            // hl=0
            *(uint4*)(base + 1024) = lv;   // hl=1
        }
    }
    __syncthreads();   // the ONLY barrier before the epilogue

    float bv1[2] = { NINF, NINF };
    float bv2[2] = { NINF, NINF };
    int   bi1[2] = { 0x7FFFFFFF, 0x7FFFFFFF };

    for (int cc = 0; cc < 4; ++cc) {
        f32x16 acc[2][2];
#pragma unroll
        for (int r = 0; r < 16; ++r) {
            int code0 = cc * 256 + w * 64 + (r & 3) + 8 * (r >> 2) + 4 * kg;
            float iA = e2n[code0];
            float iB = e2n[code0 + 32];
            acc[0][0][r] = iA; acc[0][1][r] = iA;
            acc[1][0][r] = iB; acc[1][1][r] = iB;
        }

        const uint4* ebase = ehat + (size_t)(cc * 16) * 512 + w * 128 + lane;
        uint4 ea0 = ebase[0],   ea1 = ebase[64];
        uint4 eb0 = ebase[512], eb1 = ebase[512 + 64];
#pragma unroll
        for (int ks = 0; ks < 16; ++ks) {
            uint4 en0 = {0,0,0,0}, en1 = {0,0,0,0};
            if (ks < 14) {
                en0 = ebase[(ks + 2) * 512];
                en1 = ebase[(ks + 2) * 512 + 64];
            }
            const char* q0 = XS + ks * 2048 + kg * 512 + l31 * 16;          // g=0
            const char* q1 = XS + 32768 + ks * 2048 + kg * 512 + l31 * 16;  // g=1
            f16x8 Bh0 = *(const f16x8*)q0,  Bl0 = *(const f16x8*)(q0 + 1024);
            f16x8 Bh1 = *(const f16x8*)q1,  Bl1 = *(const f16x8*)(q1 + 1024);
            U16 a0; a0.u = ea0;
            U16 a1; a1.u = ea1;
            acc[0][0] = __builtin_amdgcn_mfma_f32_32x32x16_f16(a0.h, Bh0, acc[0][0], 0, 0, 0);
            acc[0][1] = __builtin_amdgcn_mfma_f32_32x32x16_f16(a0.h, Bh1, acc[0][1], 0, 0, 0);
            acc[1][0] = __builtin_amdgcn_mfma_f32_32x32x16_f16(a1.h, Bh0, acc[1][0], 0, 0, 0);
            acc[1][1] = __builtin_amdgcn_mfma_f32_32x32x16_f16(a1.h, Bh1, acc[1][1], 0, 0, 0);
            acc[0][0] = __builtin_amdgcn_mfma_f32_32x32x16_f16(a0.h, Bl0, acc[0][0], 0, 0, 0);
            acc[0][1] = __builtin_amdgcn_mfma_f32_32x32x16_f16(a0.h, Bl1, acc[0][1], 0, 0, 0);
            acc[1][0] = __builtin_amdgcn_mfma_f32_32x32x16_f16(a1.h, Bl0, acc[1][0], 0, 0, 0);
            acc[1][1] = __builtin_amdgcn_mfma_f32_32x32x16_f16(a1.h, Bl1, acc[1][1], 0, 0, 0);
            ea0 = eb0; ea1 = eb1;
            eb0 = en0; eb1 = en1;
        }

        // ---- per-cc branchless top-2 + index ----
#pragma unroll
        for (int pf = 0; pf < 2; ++pf) {
            float m1 = NINF, m2 = NINF;
#pragma unroll
            for (int cf = 0; cf < 2; ++cf)
#pragma unroll
                for (int r = 0; r < 16; ++r) {
                    float v = acc[cf][pf][r];
                    m2 = fmaxf(m2, fminf(v, m1));
                    m1 = fmaxf(m1, v);
                }
            int idx = 0x7FFFFFFF;
#pragma unroll
            for (int cf = 0; cf < 2; ++cf)
#pragma unroll
                for (int r = 0; r < 16; ++r) {
                    float v = acc[cf][pf][r];
                    int code = cc * 256 + w * 64 + cf * 32 + (r & 3) + 8 * (r >> 2) + 4 * kg;
                    idx = (v == m1 && code < idx) ? code : idx;
                }
            // merge across the two kg halves
            float om1 = __shfl_xor(m1, 32, 64);
            float om2 = __shfl_xor(m2, 32, 64);
            int   oid = __shfl_xor(idx, 32, 64);
            float nm2 = fmaxf(fmaxf(m2, om2), fminf(m1, om1));
            bool tk = (om1 > m1) || (om1 == m1 && oid < idx);
            m1 = tk ? om1 : m1; idx = tk ? oid : idx; m2 = nm2;
            // merge into running best
            float rm2 = fmaxf(fmaxf(bv2[pf], m2), fminf(bv1[pf], m1));
            bool tk2 = (m1 > bv1[pf]) || (m1 == bv1[pf] && idx < bi1[pf]);
            bv1[pf] = tk2 ? m1 : bv1[pf];
            bi1[pf] = tk2 ? idx : bi1[pf];
            bv2[pf] = rm2;
        }
    }

    // ---- cross-wave merge (reuse XS as scratch) ----
    __syncthreads();
    float* sv = (float*)XS;
    float* sw = (float*)(XS + 1024);
    int*   si = (int*)(XS + 2048);
    if (lane < 32) {
#pragma unroll
        for (int pf = 0; pf < 2; ++pf) {
            int pix = pf * 32 + l31;
            sv[pix * 4 + w] = bv1[pf];
            sw[pix * 4 + w] = bv2[pf];
            si[pix * 4 + w] = bi1[pf];
        }
    }
    __syncthreads();
    if (t < 64) {
        float V1 = NINF, V2 = NINF; int I1 = 0x7FFFFFFF;
#pragma unroll
        for (int q = 0; q < 4; ++q) {
            float a1 = sv[t * 4 + q], a2 = sw[t * 4 + q]; int ai = si[t * 4 + q];
            float m2n = fmaxf(fmaxf(V2, a2), fminf(V1, a1));
            bool tk = (a1 > V1) || (a1 == V1 && ai < I1);
            V1 = tk ? a1 : V1; I1 = tk ? ai : I1; V2 = m2n;
        }
        ind[pix0 + t] = I1;
        if (V1 - V2 < TAU) {
            int pos = atomicAdd(count, 1);
            list[pos] = pix0 + t;
        }
    }
}

// ---------------- fixup: exact f32 re-argmin for flagged pixels ----------------
__global__ void fixup_kernel(const float* __restrict__ x, const float* __restrict__ embed,
                             const float* __restrict__ e2, int* __restrict__ ind,
                             const int* __restrict__ count, const int* __restrict__ list) {
    __shared__ float swv[4];
    __shared__ int   swi[4];
    int nf = *count;
    for (int ii = blockIdx.x; ii < nf; ii += gridDim.x) {
        int pix = list[ii];
        int b = pix >> 10, hw = pix & 1023;
        const float* xr = x + (size_t)b * (DDIM * HWSZ) + hw;
        int c0 = threadIdx.x;
        float d0 = 0, d1 = 0, d2 = 0, d3 = 0;
        for (int d = 0; d < DDIM; ++d) {
            float xv = xr[(size_t)d * HWSZ];
            const float* er = embed + (size_t)d * KCODES + c0;
            d0 = fmaf(xv, er[0],   d0);
            d1 = fmaf(xv, er[256], d1);
            d2 = fmaf(xv, er[512], d2);
            d3 = fmaf(xv, er[768], d3);
        }
        float bv = -2.f * d0 + e2[c0]; int bi = c0;
        float w1 = -2.f * d1 + e2[c0 + 256]; if (w1 < bv || (w1 == bv && c0 + 256 < bi)) { bv = w1; bi = c0 + 256; }
        float w2 = -2.f * d2 + e2[c0 + 512]; if (w2 < bv || (w2 == bv && c0 + 512 < bi)) { bv = w2; bi = c0 + 512; }
        float w3 = -2.f * d3 + e2[c0 + 768]; if (w3 < bv || (w3 == bv && c0 + 768 < bi)) { bv = w3; bi = c0 + 768; }
        for (int m = 1; m <= 32; m <<= 1) {
            float ov = __shfl_xor(bv, m, 64);
            int   oi = __shfl_xor(bi, m, 64);
            if (ov < bv || (ov == bv && oi < bi)) { bv = ov; bi = oi; }
        }
        if ((threadIdx.x & 63) == 0) { swv[threadIdx.x >> 6] = bv; swi[threadIdx.x >> 6] = bi; }
        __syncthreads();
        if (threadIdx.x == 0) {
            float V = swv[0]; int I = swi[0];
            for (int q = 1; q < 4; ++q)
                if (swv[q] < V || (swv[q] == V && swi[q] < I)) { V = swv[q]; I = swi[q]; }
            ind[pix] = I;
        }
        __syncthreads();
    }
}

// ---------------- gather: write both outputs, float4 ----------------
__global__ void gather_kernel(const float* __restrict__ embed, const int* __restrict__ ind,
                              float* __restrict__ out) {
    unsigned tid = blockIdx.x * 256u + threadIdx.x;   // 2^22 threads, 4 hw each
    unsigned hw4 = (tid & 255u) * 4u;
    unsigned bd  = tid >> 8;            // b*256 + d
    unsigned d   = bd & 255u, b = bd >> 8;
    const int4 idx = *(const int4*)&ind[(b << 10) + hw4];
    const float* er = embed + ((size_t)d << 10);
    float4 v;
    v.x = er[idx.x]; v.y = er[idx.y]; v.z = er[idx.z]; v.w = er[idx.w];
    size_t o = ((size_t)bd << 10) + hw4;
    *(float4*)&out[o] = v;
    *(float4*)&out[o + (1u << 24)] = v;
}

extern "C" void kernel_launch(void* const* d_in, const int* in_sizes, int n_in,
                              void* d_out, int out_size, void* d_ws, size_t ws_size,
                              hipStream_t stream) {
    const float* x     = (const float*)d_in[0];
    const float* embed = (const float*)d_in[1];
    float* out = (float*)d_out;
    char* ws = (char*)d_ws;

    int*   ind   = (int*)ws;                         // 262144 B
    float* e2    = (float*)(ws + 262144);            // 4096 B
    float* e2n   = (float*)(ws + 266240);            // 4096 B
    uint4* ehat  = (uint4*)(ws + 270336);            // 524288 B
    int*   count = (int*)(ws + 794624);              // 4 B
    int*   list  = (int*)(ws + 794628);              // up to 256 KiB

    hipMemsetAsync(count, 0, 4, stream);
    e2_kernel<<<16, 256, 0, stream>>>(embed, e2, e2n);
    prep_e<<<128, 256, 0, stream>>>(embed, ehat);
    vq_main<<<NROWS / 64, 256, 0, stream>>>(x, ehat, e2n, ind, count, list);
    fixup_kernel<<<512, 256, 0, stream>>>(x, embed, e2, ind, count, list);
    gather_kernel<<<(1u << 22) / 256, 256, 0, stream>>>(embed, ind, out);
}

// Round 5
// 132.669 us; speedup vs baseline: 1.7247x; 1.7247x over previous
//
#include <hip/hip_runtime.h>

typedef _Float16 f16x8 __attribute__((ext_vector_type(8)));
typedef float    f32x16 __attribute__((ext_vector_type(16)));

#define HWSZ   1024
#define DDIM   256
#define KCODES 1024
#define NROWS  65536
#define NSTEP  34        // 2 cc * 17 ks (17th = e2 fold)
#define TAU    0.07f
#define NINF  -3.4e38f

union U16 { uint4 u; f16x8 h; };

__device__ __forceinline__ void gl2lds16(const void* g, void* l) {
    __builtin_amdgcn_global_load_lds(
        (const __attribute__((address_space(1))) unsigned int*)(g),
        (__attribute__((address_space(3))) unsigned int*)(l), 16, 0, 0);
}

// ---------------- e2[k] = sum_d embed[d][k]^2 ----------------
__global__ void e2_kernel(const float* __restrict__ embed, float* __restrict__ e2) {
    int id = blockIdx.x * 256 + threadIdx.x;   // 4096 threads, 4 per code
    int k = id >> 2, q = id & 3;
    float s = 0.f;
#pragma unroll 8
    for (int dd = 0; dd < 64; ++dd) {
        float v = embed[(size_t)(q * 64 + dd) * KCODES + k];
        s = fmaf(v, v, s);
    }
    s += __shfl_xor(s, 1, 64);
    s += __shfl_xor(s, 2, 64);
    if (q == 0) e2[k] = s;
}

// ---------------- prep: fp16(embed) in MFMA-A order + e2-fold step ----------------
// ehat[estep*1024 + cfg*64 + slot]: estep = cc*17+ks, code = cc*512+cfg*32+(slot&31)
// ks<16: d = ks*16+(slot>>5)*8+j ; ks==16: j0 holds -e2/2 split hi(kg0)/lo(kg1)
__global__ void prep_e(const float* __restrict__ embed, const float* __restrict__ e2,
                       uint4* __restrict__ ehat) {
    int id = blockIdx.x * 256 + threadIdx.x;   // 34816
    if (id >= NSTEP * 1024) return;
    int slot = id & 63;
    int cfg  = (id >> 6) & 15;
    int estep = id >> 10;
    int cc = estep / 17, ks = estep % 17;
    int code = cc * 512 + cfg * 32 + (slot & 31);
    int kgp  = slot >> 5;
    _Float16 h[8];
    if (ks < 16) {
#pragma unroll
        for (int j = 0; j < 8; ++j)
            h[j] = (_Float16)embed[(size_t)(ks * 16 + kgp * 8 + j) * KCODES + code];
    } else {
        float e2n = -0.5f * e2[code];
        _Float16 hi = (_Float16)e2n;
#pragma unroll
        for (int j = 0; j < 8; ++j) h[j] = (_Float16)0.f;
        h[0] = (kgp == 0) ? hi : (_Float16)(e2n - (float)hi);
    }
    uint4 o;
    __builtin_memcpy(&o, h, 16);
    ehat[id] = o;
}

// ---------------- main: fp16 GEMM, E triple-buffered LDS, counted vmcnt ----------------
__global__ __launch_bounds__(256, 2)
void vq_main(const float* __restrict__ x, const uint4* __restrict__ ehat,
             int* __restrict__ ind, int* __restrict__ count, int* __restrict__ list) {
    __shared__ __align__(16) char smem[81920];
    char* XS = smem;            // 32 KB: [ks16][pf2][kg2][pl32] x 16B
    char* EB = smem + 32768;    // 3 x 16 KB: [cfg16][slot64] x 16B

    const int t    = threadIdx.x;
    const int lane = t & 63;
    const int w    = t >> 6;
    const int kg   = lane >> 5;
    const int l31  = lane & 31;

    const int pix0 = blockIdx.x * 64;
    const int b0   = pix0 >> 10;
    const int hw0  = pix0 & 1023;
    const float* xb = x + (size_t)b0 * (DDIM * HWSZ) + hw0;

    // ---- stage X tile: f32 -> fp16 hi, B-frag layout ----
    {
        int pix = t & 63, dq = t >> 6;
        int pf = pix >> 5, pl = pix & 31;
        const float* xpix = xb + pix;
#pragma unroll
        for (int uu = 0; uu < 8; ++uu) {
            int unit = uu * 4 + dq;            // 0..31: ks=unit>>1, kg=unit&1
            int d0 = unit * 8;
            _Float16 h[8];
#pragma unroll
            for (int j = 0; j < 8; ++j)
                h[j] = (_Float16)xpix[(size_t)(d0 + j) * HWSZ];
            uint4 hv;
            __builtin_memcpy(&hv, h, 16);
            *(uint4*)(XS + ((((unit >> 1) * 4 + pf * 2 + (unit & 1)) * 32 + pl) << 4)) = hv;
        }
    }
    __syncthreads();   // XS ready; vmcnt drained by compiler here

    // ---- prologue: DMA batch 0 ----
    {
        const char* gs = (const char*)ehat;
#pragma unroll
        for (int i = 0; i < 4; ++i)
            gl2lds16(gs + i * 4096 + t * 16, EB + i * 4096 + t * 16);
    }

    f16x8 onefrag = {};
    onefrag[0] = (_Float16)1.0f;

    float bv1[2] = { NINF, NINF };
    float bv2[2] = { NINF, NINF };
    int   bi1[2] = { 0x7FFFFFFF, 0x7FFFFFFF };

    for (int cc = 0; cc < 2; ++cc) {
        f32x16 acc[4][2];
#pragma unroll
        for (int cf = 0; cf < 4; ++cf)
#pragma unroll
            for (int pf = 0; pf < 2; ++pf)
#pragma unroll
                for (int e = 0; e < 16; ++e) acc[cf][pf][e] = 0.f;

        for (int ks = 0; ks < 17; ++ks) {
            int s = cc * 17 + ks;
            if (s + 1 < NSTEP) {
                const char* gs = (const char*)ehat + ((size_t)(s + 1) << 14);
                char* ld = EB + (((s + 1) % 3) << 14);
#pragma unroll
                for (int i = 0; i < 4; ++i)
                    gl2lds16(gs + i * 4096 + t * 16, ld + i * 4096 + t * 16);
                asm volatile("s_waitcnt vmcnt(4)" ::: "memory");   // batch s landed
            } else {
                asm volatile("s_waitcnt vmcnt(0)" ::: "memory");
            }
            __builtin_amdgcn_s_barrier();
            __builtin_amdgcn_sched_barrier(0);

            const char* eb = EB + ((s % 3) << 14);
            U16 A[4];
#pragma unroll
            for (int cf = 0; cf < 4; ++cf)
                A[cf].u = *(const uint4*)(eb + (((w * 4 + cf) * 64 + lane) << 4));
            f16x8 B[2];
            if (ks < 16) {
#pragma unroll
                for (int pf = 0; pf < 2; ++pf)
                    B[pf] = *(const f16x8*)(XS + (((ks * 4 + pf * 2 + kg) * 32 + l31) << 4));
            } else {
                B[0] = onefrag; B[1] = onefrag;
            }
#pragma unroll
            for (int cf = 0; cf < 4; ++cf)
#pragma unroll
                for (int pf = 0; pf < 2; ++pf)
                    acc[cf][pf] = __builtin_amdgcn_mfma_f32_32x32x16_f16(A[cf].h, B[pf], acc[cf][pf], 0, 0, 0);
        }

        // ---- per-cc branchless top-2 + lowest-index ----
#pragma unroll
        for (int pf = 0; pf < 2; ++pf) {
            float m1 = NINF, m2 = NINF;
#pragma unroll
            for (int cf = 0; cf < 4; ++cf)
#pragma unroll
                for (int r = 0; r < 16; ++r) {
                    float v = acc[cf][pf][r];
                    m2 = fmaxf(m2, fminf(v, m1));
                    m1 = fmaxf(m1, v);
                }
            int idx = 0x7FFFFFFF;
#pragma unroll
            for (int cf = 0; cf < 4; ++cf)
#pragma unroll
                for (int r = 0; r < 16; ++r) {
                    float v = acc[cf][pf][r];
                    int code = cc * 512 + w * 128 + cf * 32 + (r & 3) + 8 * (r >> 2) + 4 * kg;
                    idx = (v == m1 && code < idx) ? code : idx;
                }
            float om1 = __shfl_xor(m1, 32, 64);
            float om2 = __shfl_xor(m2, 32, 64);
            int   oid = __shfl_xor(idx, 32, 64);
            float nm2 = fmaxf(fmaxf(m2, om2), fminf(m1, om1));
            bool tk = (om1 > m1) || (om1 == m1 && oid < idx);
            m1 = tk ? om1 : m1; idx = tk ? oid : idx; m2 = nm2;
            float rm2 = fmaxf(fmaxf(bv2[pf], m2), fminf(bv1[pf], m1));
            bool tk2 = (m1 > bv1[pf]) || (m1 == bv1[pf] && idx < bi1[pf]);
            bv1[pf] = tk2 ? m1 : bv1[pf];
            bi1[pf] = tk2 ? idx : bi1[pf];
            bv2[pf] = rm2;
        }
    }

    // ---- cross-wave merge (reuse XS after full barrier) ----
    __syncthreads();
    float* sv = (float*)XS;
    float* sw = (float*)(XS + 1024);
    int*   si = (int*)(XS + 2048);
    if (lane < 32) {
#pragma unroll
        for (int pf = 0; pf < 2; ++pf) {
            int pix = pf * 32 + l31;
            sv[pix * 4 + w] = bv1[pf];
            sw[pix * 4 + w] = bv2[pf];
            si[pix * 4 + w] = bi1[pf];
        }
    }
    __syncthreads();
    if (t < 64) {
        float V1 = NINF, V2 = NINF; int I1 = 0x7FFFFFFF;
#pragma unroll
        for (int q = 0; q < 4; ++q) {
            float a1 = sv[t * 4 + q], a2 = sw[t * 4 + q]; int ai = si[t * 4 + q];
            float m2n = fmaxf(fmaxf(V2, a2), fminf(V1, a1));
            bool tk = (a1 > V1) || (a1 == V1 && ai < I1);
            V1 = tk ? a1 : V1; I1 = tk ? ai : I1; V2 = m2n;
        }
        ind[pix0 + t] = I1;
        if (V1 - V2 < TAU) {
            int pos = atomicAdd(count, 1);
            list[pos] = pix0 + t;
        }
    }
}

// ---------------- fixup: exact f32 re-argmin, 8 pixels/block share embed reads ----------------
__global__ __launch_bounds__(256)
void fixup_kernel(const float* __restrict__ x, const float* __restrict__ embed,
                  const float* __restrict__ e2, int* __restrict__ ind,
                  const int* __restrict__ count, const int* __restrict__ list) {
    __shared__ float XL[8][DDIM];
    __shared__ float cv[8][4];
    __shared__ int   ci[8][4];
    const int t = threadIdx.x;
    const int nf = *count;
    for (int base = blockIdx.x * 8; base < nf; base += gridDim.x * 8) {
        int m = min(8, nf - base);
        {
            int p = t >> 5, idx = t & 31;
            if (p < m) {
                int pix = list[base + p];
                int b = pix >> 10, hw = pix & 1023;
                const float* xr = x + (size_t)b * (DDIM * HWSZ) + hw;
#pragma unroll
                for (int j = 0; j < 8; ++j) {
                    int d = idx * 8 + j;
                    XL[p][d] = xr[(size_t)d * HWSZ];
                }
            }
        }
        __syncthreads();
        const int c0 = t * 4;
        float4 a[8];
#pragma unroll
        for (int p = 0; p < 8; ++p) a[p] = make_float4(0.f, 0.f, 0.f, 0.f);
        for (int d4 = 0; d4 < DDIM; d4 += 4) {
            float4 ev0 = *(const float4*)&embed[(size_t)(d4 + 0) * KCODES + c0];
            float4 ev1 = *(const float4*)&embed[(size_t)(d4 + 1) * KCODES + c0];
            float4 ev2 = *(const float4*)&embed[(size_t)(d4 + 2) * KCODES + c0];
            float4 ev3 = *(const float4*)&embed[(size_t)(d4 + 3) * KCODES + c0];
#pragma unroll
            for (int p = 0; p < 8; ++p) {
                float4 xq = *(const float4*)&XL[p][d4];
                a[p].x = fmaf(xq.x, ev0.x, a[p].x); a[p].y = fmaf(xq.x, ev0.y, a[p].y);
                a[p].z = fmaf(xq.x, ev0.z, a[p].z); a[p].w = fmaf(xq.x, ev0.w, a[p].w);
                a[p].x = fmaf(xq.y, ev1.x, a[p].x); a[p].y = fmaf(xq.y, ev1.y, a[p].y);
                a[p].z = fmaf(xq.y, ev1.z, a[p].z); a[p].w = fmaf(xq.y, ev1.w, a[p].w);
                a[p].x = fmaf(xq.z, ev2.x, a[p].x); a[p].y = fmaf(xq.z, ev2.y, a[p].y);
                a[p].z = fmaf(xq.z, ev2.z, a[p].z); a[p].w = fmaf(xq.z, ev2.w, a[p].w);
                a[p].x = fmaf(xq.w, ev3.x, a[p].x); a[p].y = fmaf(xq.w, ev3.y, a[p].y);
                a[p].z = fmaf(xq.w, ev3.z, a[p].z); a[p].w = fmaf(xq.w, ev3.w, a[p].w);
            }
        }
        float4 e2q = *(const float4*)&e2[c0];
#pragma unroll
        for (int p = 0; p < 8; ++p) {
            float bv = e2q.x - 2.f * a[p].x; int bi = c0;
            float d1 = e2q.y - 2.f * a[p].y; if (d1 < bv) { bv = d1; bi = c0 + 1; }
            float d2 = e2q.z - 2.f * a[p].z; if (d2 < bv) { bv = d2; bi = c0 + 2; }
            float d3 = e2q.w - 2.f * a[p].w; if (d3 < bv) { bv = d3; bi = c0 + 3; }
#pragma unroll
            for (int mm = 1; mm <= 32; mm <<= 1) {
                float ov = __shfl_xor(bv, mm, 64);
                int   oi = __shfl_xor(bi, mm, 64);
                if (ov < bv || (ov == bv && oi < bi)) { bv = ov; bi = oi; }
            }
            if ((t & 63) == 0) { cv[p][t >> 6] = bv; ci[p][t >> 6] = bi; }
        }
        __syncthreads();
        if (t < m) {
            float V = cv[t][0]; int I = ci[t][0];
#pragma unroll
            for (int q = 1; q < 4; ++q)
                if (cv[t][q] < V || (cv[t][q] == V && ci[t][q] < I)) { V = cv[t][q]; I = ci[t][q]; }
            ind[list[base + t]] = I;
        }
        __syncthreads();
    }
}

// ---------------- gather: write both outputs, float4 ----------------
__global__ void gather_kernel(const float* __restrict__ embed, const int* __restrict__ ind,
                              float* __restrict__ out) {
    unsigned tid = blockIdx.x * 256u + threadIdx.x;
    unsigned hw4 = (tid & 255u) * 4u;
    unsigned bd  = tid >> 8;
    unsigned d   = bd & 255u, b = bd >> 8;
    const int4 idx = *(const int4*)&ind[(b << 10) + hw4];
    const float* er = embed + ((size_t)d << 10);
    float4 v;
    v.x = er[idx.x]; v.y = er[idx.y]; v.z = er[idx.z]; v.w = er[idx.w];
    size_t o = ((size_t)bd << 10) + hw4;
    *(float4*)&out[o] = v;
    *(float4*)&out[o + (1u << 24)] = v;
}

extern "C" void kernel_launch(void* const* d_in, const int* in_sizes, int n_in,
                              void* d_out, int out_size, void* d_ws, size_t ws_size,
                              hipStream_t stream) {
    const float* x     = (const float*)d_in[0];
    const float* embed = (const float*)d_in[1];
    float* out = (float*)d_out;
    char* ws = (char*)d_ws;

    int*   ind   = (int*)ws;                     // 262144 B
    float* e2    = (float*)(ws + 262144);        // 4096 B
    uint4* ehat  = (uint4*)(ws + 266240);        // 557056 B
    int*   count = (int*)(ws + 823296);          // 4 B
    int*   list  = (int*)(ws + 823300);          // plenty

    hipMemsetAsync(count, 0, 4, stream);
    e2_kernel<<<16, 256, 0, stream>>>(embed, e2);
    prep_e<<<136, 256, 0, stream>>>(embed, e2, ehat);
    vq_main<<<NROWS / 64, 256, 0, stream>>>(x, ehat, ind, count, list);
    fixup_kernel<<<320, 256, 0, stream>>>(x, embed, e2, ind, count, list);
    gather_kernel<<<(1u << 22) / 256, 256, 0, stream>>>(embed, ind, out);
}